// Round 7
// baseline (268.758 us; speedup 1.0000x reference)
//
#include <hip/hip_runtime.h>
#include <cstdint>
#include <cstddef>

// ---- types ----
typedef __attribute__((ext_vector_type(8))) short short8;       // 8 bf16 (4 VGPR) MFMA frag
typedef __attribute__((ext_vector_type(4))) float floatx4;      // MFMA accumulator
typedef __attribute__((ext_vector_type(4))) unsigned short ushortx4; // 8B packed bf16 store
typedef __attribute__((ext_vector_type(4))) unsigned int uintx4;     // 16B vector ld/st
typedef __attribute__((ext_vector_type(2))) unsigned int uintx2;     // 8B vector st

#define MFMA16(a, b, c) __builtin_amdgcn_mfma_f32_16x16x32_bf16((a), (b), (c), 0, 0, 0)

__device__ __forceinline__ unsigned short f2bf(float f) {
  unsigned int u = __builtin_bit_cast(unsigned int, f);
  u += 0x7fffu + ((u >> 16) & 1u);          // RNE
  return (unsigned short)(u >> 16);
}

__device__ __forceinline__ unsigned int pk_bf16(float a, float b) {
  return (unsigned int)f2bf(a) | ((unsigned int)f2bf(b) << 16);   // lo=a, hi=b
}

typedef __attribute__((address_space(1))) void gvoid_t;
typedef __attribute__((address_space(3))) void svoid_t;
__device__ __forceinline__ void gload_lds16(const void* g, void* l) {
  // LDS dest = wave-uniform base + lane*16; global side is per-lane addresses.
  __builtin_amdgcn_global_load_lds((gvoid_t*)(uintptr_t)g, (svoid_t*)(uintptr_t)l, 16, 0, 0);
}

// ---------------- convert x: fp32 -> bf16 ----------------
__global__ void convert_x(const float* __restrict__ x, unsigned short* __restrict__ xb) {
  int i = (blockIdx.x * 256 + threadIdx.x) * 4;
  floatx4 v = *(const floatx4*)(x + i);
  ushortx4 o;
  o[0] = f2bf(v[0]); o[1] = f2bf(v[1]); o[2] = f2bf(v[2]); o[3] = f2bf(v[3]);
  *(ushortx4*)(xb + i) = o;
}

// ---------------- transpose weights -> bf16 N x K ----------------
__global__ void transpose_w(const float* __restrict__ Wq, const float* __restrict__ Wk,
                            const float* __restrict__ Wv, const float* __restrict__ Wo,
                            unsigned short* __restrict__ Wqkvt, unsigned short* __restrict__ Wot) {
  __shared__ float tile[32][33];
  int z = blockIdx.z;
  const float* W = (z == 0) ? Wq : (z == 1) ? Wk : (z == 2) ? Wv : Wo;
  unsigned short* out = (z == 3) ? Wot : (Wqkvt + (size_t)z * 1024 * 1024);
  int n0 = blockIdx.x * 32, k0 = blockIdx.y * 32;
  int tx = threadIdx.x, ty = threadIdx.y;            // block (32,8)
#pragma unroll
  for (int j = 0; j < 4; ++j)
    tile[ty + j * 8][tx] = W[(size_t)(k0 + ty + j * 8) * 1024 + n0 + tx];
  __syncthreads();
#pragma unroll
  for (int j = 0; j < 4; ++j)
    out[(size_t)(n0 + ty + j * 8) * 1024 + k0 + tx] = f2bf(tile[tx][ty + j * 8]);
}

// ---------------- GEMM core v2: BK=64, XOR-swizzled LDS ----------------
#define GEMM_PROLOGUE()                                                        \
  __shared__ __align__(16) unsigned short As[128 * 64];                        \
  __shared__ __align__(16) unsigned short Bs[128 * 64];                        \
  const int tid = threadIdx.x;                                                 \
  const int lane = tid & 63;                                                   \
  const int wid = tid >> 6;                                                    \
  const int col = lane & 15;                                                   \
  const int quad = lane >> 4;                                                  \
  const int m0 = blockIdx.x * 128;                                             \
  const int n0 = blockIdx.y * 128;                                             \
  const int wm = wid >> 1;                                                     \
  const int wn = wid & 1;                                                      \
  floatx4 acc[4][4];                                                           \
  _Pragma("unroll") for (int i = 0; i < 4; ++i)                                \
      _Pragma("unroll") for (int j = 0; j < 4; ++j)                            \
          acc[i][j] = (floatx4)(0.f);                                          \
  _Pragma("unroll 1") for (int kt = 0; kt < 16; ++kt) {                        \
    __syncthreads();                                                           \
    _Pragma("unroll") for (int call = 0; call < 4; ++call) {                   \
      int c = call * 256 + tid;                                                \
      int r = c >> 3, ch = c & 7;                                              \
      int gk = kt * 64 + ((ch ^ (r & 7)) * 8);                                 \
      gload_lds16(A + (size_t)(m0 + r) * 1024 + gk,                            \
                  As + (size_t)(call * 256 + wid * 64) * 8);                   \
      gload_lds16(Bt + (size_t)(n0 + r) * 1024 + gk,                           \
                  Bs + (size_t)(call * 256 + wid * 64) * 8);                   \
    }                                                                          \
    __syncthreads();                                                           \
    _Pragma("unroll") for (int ks = 0; ks < 2; ++ks) {                         \
      short8 af[4], bf[4];                                                     \
      _Pragma("unroll") for (int rt = 0; rt < 4; ++rt) {                       \
        int row = wm * 64 + rt * 16 + col;                                     \
        af[rt] = *(const short8*)&As[row * 64 + (((ks * 4 + quad) ^ (row & 7)) * 8)]; \
      }                                                                        \
      _Pragma("unroll") for (int ct = 0; ct < 4; ++ct) {                       \
        int row = wn * 64 + ct * 16 + col;                                     \
        bf[ct] = *(const short8*)&Bs[row * 64 + (((ks * 4 + quad) ^ (row & 7)) * 8)]; \
      }                                                                        \
      _Pragma("unroll") for (int rt = 0; rt < 4; ++rt)                         \
          _Pragma("unroll") for (int ct = 0; ct < 4; ++ct)                     \
              acc[rt][ct] = MFMA16(af[rt], bf[ct], acc[rt][ct]);               \
    }                                                                          \
  }

__global__ __launch_bounds__(256)
void gemm_qkv(const unsigned short* __restrict__ A, const unsigned short* __restrict__ Bt,
              const float* __restrict__ bq, const float* __restrict__ bk,
              const float* __restrict__ bv,
              unsigned short* __restrict__ Qo, unsigned short* __restrict__ Ko,
              unsigned short* __restrict__ Vo) {
  GEMM_PROLOGUE()
  const int nseg = n0 >> 10;
  const float* bias = (nseg == 0) ? bq : ((nseg == 1) ? bk : bv);
#pragma unroll
  for (int rt = 0; rt < 4; ++rt) {
#pragma unroll
    for (int ct = 0; ct < 4; ++ct) {
      int mg = m0 + wm * 64 + rt * 16 + quad * 4;
      int ng = n0 + wn * 64 + ct * 16 + col;
      int c = ng & 1023;
      int hh = c >> 6, hd = c & 63;
      int b_ = mg >> 11, s = mg & 2047;
      float bb = bias[c];
      if (nseg == 2) {
        ushortx4 pk;
#pragma unroll
        for (int i = 0; i < 4; ++i) pk[i] = f2bf(acc[rt][ct][i] + bb);
        *(ushortx4*)&Vo[(size_t)(b_ * 16 + hh) * 131072 + (size_t)hd * 2048 + s] = pk;
      } else {
        unsigned short* dst =
            ((nseg == 0) ? Qo : Ko) + ((size_t)(b_ * 16 + hh) * 2048 + s) * 64 + hd;
        float scl = (nseg == 0) ? 0.125f : 1.0f;    // fold 1/sqrt(64) into Q
#pragma unroll
        for (int i = 0; i < 4; ++i) dst[(size_t)i * 64] = f2bf((acc[rt][ct][i] + bb) * scl);
      }
    }
  }
}

__global__ __launch_bounds__(256)
void gemm_out(const unsigned short* __restrict__ A, const unsigned short* __restrict__ Bt,
              const float* __restrict__ bo, float* __restrict__ Out) {
  GEMM_PROLOGUE()
#pragma unroll
  for (int rt = 0; rt < 4; ++rt) {
#pragma unroll
    for (int ct = 0; ct < 4; ++ct) {
      int mg = m0 + wm * 64 + rt * 16 + quad * 4;
      int ng = n0 + wn * 64 + ct * 16 + col;
      float bb = bo[ng];
#pragma unroll
      for (int i = 0; i < 4; ++i)
        Out[(size_t)(mg + i) * 1024 + ng] = acc[rt][ct][i] + bb;
    }
  }
}

// ---------------- flash attention v5: 1-wave blocks, no barriers ----------------
// Block = 1 wave (64 thr). Paired q-tiles j=pr and 63-pr -> exactly 33 kv-chunks
// per block (perfect balance); grid 1024 -> ~16+ waves/CU for latency hiding.
// K frags and V^T frags read directly from global (contiguous b128; K=[s][hd],
// V stored [hd][s]). P relayout C->B-operand via wave-PRIVATE padded LDS
// (8 ds_write_b64 + 4 ds_read_b128 per chunk, no __syncthreads anywhere).
__global__ __launch_bounds__(64, 4)
void flash_attn(const unsigned short* __restrict__ Q, const unsigned short* __restrict__ K,
                const unsigned short* __restrict__ Vt, const float* __restrict__ mask,
                unsigned short* __restrict__ O) {
  __shared__ __align__(16) unsigned short Ps[32 * 72];  // [q=32][kv=64 +8 pad]

  const int lane = threadIdx.x & 63;
  const int col = lane & 15;
  const int quad = lane >> 4;
  const int bh = blockIdx.x & 31;
  const int pr = blockIdx.x >> 5;            // 0..31
  const int b = bh >> 4, h = bh & 15;

  const unsigned short* Qp = Q + (size_t)bh * 2048 * 64;
  const unsigned short* Kp = K + (size_t)bh * 2048 * 64;
  const unsigned short* Vp = Vt + (size_t)bh * 64 * 2048;
  const float* mp = mask + b * 2048;
  const floatx4 fzero = (floatx4)(0.f);

#pragma unroll 1
  for (int phase = 0; phase < 2; ++phase) {
    const int j = phase ? (63 - pr) : pr;    // q tile (32 rows)
    const int q0 = j * 32;
    const int C = (j >> 1) + 1;              // kv chunks of 64

    // Q fragments (B-operand): n=q=nt*16+col, k=hd=ks*32+quad*8+j'
    short8 qf[2][2];
#pragma unroll
    for (int nt = 0; nt < 2; ++nt)
#pragma unroll
      for (int ks = 0; ks < 2; ++ks)
        qf[nt][ks] = *(const short8*)&Qp[(size_t)(q0 + nt * 16 + col) * 64 + ks * 32 + quad * 8];

    floatx4 o[4][2];
#pragma unroll
    for (int dt = 0; dt < 4; ++dt) {
      o[dt][0] = fzero;
      o[dt][1] = fzero;
    }
    float mrow[2] = {-1e30f, -1e30f};
    float lrow[2] = {0.f, 0.f};

#pragma unroll 1
    for (int t = 0; t < C; ++t) {
      const int kv0 = t * 64;
      // K fragments (A-op): m=kv=mt*16+col, k=hd
      short8 kf[4][2];
#pragma unroll
      for (int mt = 0; mt < 4; ++mt)
#pragma unroll
        for (int ks = 0; ks < 2; ++ks)
          kf[mt][ks] = *(const short8*)&Kp[(size_t)(kv0 + mt * 16 + col) * 64 + ks * 32 + quad * 8];
      // V^T fragments (A-op): m=d=dt*16+col, k=kv
      short8 vf[4][2];
#pragma unroll
      for (int dt = 0; dt < 4; ++dt)
#pragma unroll
        for (int ks = 0; ks < 2; ++ks)
          vf[dt][ks] = *(const short8*)&Vp[(size_t)(dt * 16 + col) * 2048 + kv0 + ks * 32 + quad * 8];
      // padding-mask bias (kv = mt*16 + quad*4 + i)
      floatx4 mb[4];
#pragma unroll
      for (int mt = 0; mt < 4; ++mt) {
        floatx4 mm = *(const floatx4*)&mp[kv0 + mt * 16 + quad * 4];
        mb[mt] = (mm - 1.0f) * 1.0e9f;        // == (1-m)*-1e9
      }

      // S^T = K*Q^T : per lane q=nt*16+col, kv=mt*16+quad*4+reg
      floatx4 sc[4][2];
#pragma unroll
      for (int mt = 0; mt < 4; ++mt)
#pragma unroll
        for (int nt = 0; nt < 2; ++nt) {
          floatx4 s = MFMA16(kf[mt][0], qf[nt][0], fzero);
          s = MFMA16(kf[mt][1], qf[nt][1], s);
          sc[mt][nt] = s + mb[mt];
        }
      if (t == C - 1) {  // causal diagonal: exactly -1e9 like the reference
#pragma unroll
        for (int mt = 0; mt < 4; ++mt)
#pragma unroll
          for (int nt = 0; nt < 2; ++nt) {
            int qg = q0 + nt * 16 + col;
#pragma unroll
            for (int i = 0; i < 4; ++i)
              if (kv0 + mt * 16 + quad * 4 + i > qg) sc[mt][nt][i] = -1.0e9f;
          }
      }

      // online softmax (stats per lane-q; reduce over quad: 2 shuffles each)
#pragma unroll
      for (int nt = 0; nt < 2; ++nt) {
        float mt_ = -1e30f;
#pragma unroll
        for (int mt = 0; mt < 4; ++mt)
          mt_ = fmaxf(mt_, fmaxf(fmaxf(sc[mt][nt][0], sc[mt][nt][1]),
                                 fmaxf(sc[mt][nt][2], sc[mt][nt][3])));
        mt_ = fmaxf(mt_, __shfl_xor(mt_, 16));
        mt_ = fmaxf(mt_, __shfl_xor(mt_, 32));
        float mn = fmaxf(mrow[nt], mt_);
        float alpha = __expf(mrow[nt] - mn);
        mrow[nt] = mn;
        float sum = 0.f;
#pragma unroll
        for (int mt = 0; mt < 4; ++mt)
#pragma unroll
          for (int i = 0; i < 4; ++i) {
            float p = __expf(sc[mt][nt][i] - mn);
            sc[mt][nt][i] = p;
            sum += p;
          }
        sum += __shfl_xor(sum, 16);
        sum += __shfl_xor(sum, 32);
        lrow[nt] = lrow[nt] * alpha + sum;
#pragma unroll
        for (int dt = 0; dt < 4; ++dt) o[dt][nt] *= alpha;
      }

      // P relayout through wave-private LDS: write C-layout [q][kv] (b64),
      // read B-operand frags (b128). Row pad +8 shorts -> conflict-optimal.
#pragma unroll
      for (int mt = 0; mt < 4; ++mt)
#pragma unroll
        for (int nt = 0; nt < 2; ++nt) {
          uintx2 w;
          w[0] = pk_bf16(sc[mt][nt][0], sc[mt][nt][1]);
          w[1] = pk_bf16(sc[mt][nt][2], sc[mt][nt][3]);
          *(uintx2*)&Ps[(nt * 16 + col) * 72 + mt * 16 + quad * 4] = w;
        }
      // PV: O^T[d][q] += V^T * P^T  (DS ops are in-order within the wave)
#pragma unroll
      for (int ks = 0; ks < 2; ++ks)
#pragma unroll
        for (int nt = 0; nt < 2; ++nt) {
          short8 pf = *(const short8*)&Ps[(nt * 16 + col) * 72 + ks * 32 + quad * 8];
#pragma unroll
          for (int dt = 0; dt < 4; ++dt)
            o[dt][nt] = MFMA16(vf[dt][ks], pf, o[dt][nt]);
        }
    }

    // epilogue: O^T regs: d = dt*16 + quad*4 + i, q = nt*16 + col
#pragma unroll
    for (int nt = 0; nt < 2; ++nt) {
      float inv = 1.0f / lrow[nt];
      int qg = q0 + nt * 16 + col;
      unsigned short* dst = O + ((size_t)(b * 2048 + qg)) * 1024 + h * 64;
#pragma unroll
      for (int dt = 0; dt < 4; ++dt) {
        ushortx4 pko;
#pragma unroll
        for (int i = 0; i < 4; ++i) pko[i] = f2bf(o[dt][nt][i] * inv);
        *(ushortx4*)&dst[dt * 16 + quad * 4] = pko;
      }
    }
  }
}

// ---------------- launch ----------------
extern "C" void kernel_launch(void* const* d_in, const int* in_sizes, int n_in,
                              void* d_out, int out_size, void* d_ws, size_t ws_size,
                              hipStream_t stream) {
  (void)in_sizes; (void)n_in; (void)out_size; (void)ws_size;
  const float* x  = (const float*)d_in[0];
  const float* mask = (const float*)d_in[1];
  const float* Wq = (const float*)d_in[2];
  const float* bq = (const float*)d_in[3];
  const float* Wk = (const float*)d_in[4];
  const float* bk = (const float*)d_in[5];
  const float* Wv = (const float*)d_in[6];
  const float* bv = (const float*)d_in[7];
  const float* Wo = (const float*)d_in[8];
  const float* bo = (const float*)d_in[9];
  float* out = (float*)d_out;

  char* ws = (char*)d_ws;
  unsigned short* xb    = (unsigned short*)(ws);                    // 8 MB
  unsigned short* Wqkvt = (unsigned short*)(ws + (8u << 20));       // 6 MB
  unsigned short* Wot   = (unsigned short*)(ws + (14u << 20));      // 2 MB
  unsigned short* Qb    = (unsigned short*)(ws + (16u << 20));      // 8 MB
  unsigned short* Kb    = (unsigned short*)(ws + (24u << 20));      // 8 MB
  unsigned short* Vtb   = (unsigned short*)(ws + (32u << 20));      // 8 MB
  unsigned short* Ao    = (unsigned short*)(ws + (40u << 20));      // 8 MB (48 MB total)

  convert_x<<<4096, 256, 0, stream>>>(x, xb);
  transpose_w<<<dim3(32, 32, 4), dim3(32, 8), 0, stream>>>(Wq, Wk, Wv, Wo, Wqkvt, Wot);
  gemm_qkv<<<dim3(32, 24), 256, 0, stream>>>(xb, Wqkvt, bq, bk, bv, Qb, Kb, Vtb);
  flash_attn<<<dim3(1024), 64, 0, stream>>>(Qb, Kb, Vtb, mask, Ao);
  gemm_out<<<dim3(32, 8), 256, 0, stream>>>(Ao, Wot, bo, out);
}

// Round 8
// 197.445 us; speedup vs baseline: 1.3612x; 1.3612x over previous
//
#include <hip/hip_runtime.h>
#include <cstdint>
#include <cstddef>

// ---- types ----
typedef __attribute__((ext_vector_type(8))) short short8;       // 8 bf16 (4 VGPR) MFMA frag
typedef __attribute__((ext_vector_type(4))) float floatx4;      // MFMA accumulator
typedef __attribute__((ext_vector_type(4))) unsigned short ushortx4; // 8B packed bf16 store
typedef __attribute__((ext_vector_type(4))) unsigned int uintx4;     // 16B vector ld/st

#define MFMA16(a, b, c) __builtin_amdgcn_mfma_f32_16x16x32_bf16((a), (b), (c), 0, 0, 0)

__device__ __forceinline__ unsigned short f2bf(float f) {
  unsigned int u = __builtin_bit_cast(unsigned int, f);
  u += 0x7fffu + ((u >> 16) & 1u);          // RNE
  return (unsigned short)(u >> 16);
}

typedef __attribute__((address_space(1))) void gvoid_t;
typedef __attribute__((address_space(3))) void svoid_t;
__device__ __forceinline__ void gload_lds16(const void* g, void* l) {
  // LDS dest = wave-uniform base + lane*16; global side is per-lane addresses.
  __builtin_amdgcn_global_load_lds((gvoid_t*)(uintptr_t)g, (svoid_t*)(uintptr_t)l, 16, 0, 0);
}

// ---------------- convert x: fp32 -> bf16 ----------------
__global__ void convert_x(const float* __restrict__ x, unsigned short* __restrict__ xb) {
  int i = (blockIdx.x * 256 + threadIdx.x) * 4;
  floatx4 v = *(const floatx4*)(x + i);
  ushortx4 o;
  o[0] = f2bf(v[0]); o[1] = f2bf(v[1]); o[2] = f2bf(v[2]); o[3] = f2bf(v[3]);
  *(ushortx4*)(xb + i) = o;
}

// ---------------- transpose weights -> bf16 N x K ----------------
__global__ void transpose_w(const float* __restrict__ Wq, const float* __restrict__ Wk,
                            const float* __restrict__ Wv, const float* __restrict__ Wo,
                            unsigned short* __restrict__ Wqkvt, unsigned short* __restrict__ Wot) {
  __shared__ float tile[32][33];
  int z = blockIdx.z;
  const float* W = (z == 0) ? Wq : (z == 1) ? Wk : (z == 2) ? Wv : Wo;
  unsigned short* out = (z == 3) ? Wot : (Wqkvt + (size_t)z * 1024 * 1024);
  int n0 = blockIdx.x * 32, k0 = blockIdx.y * 32;
  int tx = threadIdx.x, ty = threadIdx.y;            // block (32,8)
#pragma unroll
  for (int j = 0; j < 4; ++j)
    tile[ty + j * 8][tx] = W[(size_t)(k0 + ty + j * 8) * 1024 + n0 + tx];
  __syncthreads();
#pragma unroll
  for (int j = 0; j < 4; ++j)
    out[(size_t)(n0 + ty + j * 8) * 1024 + k0 + tx] = f2bf(tile[tx][ty + j * 8]);
}

// ---------------- GEMM core v2: BK=64, XOR-swizzled LDS ----------------
#define GEMM_PROLOGUE()                                                        \
  __shared__ __align__(16) unsigned short As[128 * 64];                        \
  __shared__ __align__(16) unsigned short Bs[128 * 64];                        \
  const int tid = threadIdx.x;                                                 \
  const int lane = tid & 63;                                                   \
  const int wid = tid >> 6;                                                    \
  const int col = lane & 15;                                                   \
  const int quad = lane >> 4;                                                  \
  const int m0 = blockIdx.x * 128;                                             \
  const int n0 = blockIdx.y * 128;                                             \
  const int wm = wid >> 1;                                                     \
  const int wn = wid & 1;                                                      \
  floatx4 acc[4][4];                                                           \
  _Pragma("unroll") for (int i = 0; i < 4; ++i)                                \
      _Pragma("unroll") for (int j = 0; j < 4; ++j)                            \
          acc[i][j] = (floatx4)(0.f);                                          \
  _Pragma("unroll 1") for (int kt = 0; kt < 16; ++kt) {                        \
    __syncthreads();                                                           \
    _Pragma("unroll") for (int call = 0; call < 4; ++call) {                   \
      int c = call * 256 + tid;                                                \
      int r = c >> 3, ch = c & 7;                                              \
      int gk = kt * 64 + ((ch ^ (r & 7)) * 8);                                 \
      gload_lds16(A + (size_t)(m0 + r) * 1024 + gk,                            \
                  As + (size_t)(call * 256 + wid * 64) * 8);                   \
      gload_lds16(Bt + (size_t)(n0 + r) * 1024 + gk,                           \
                  Bs + (size_t)(call * 256 + wid * 64) * 8);                   \
    }                                                                          \
    __syncthreads();                                                           \
    _Pragma("unroll") for (int ks = 0; ks < 2; ++ks) {                         \
      short8 af[4], bf[4];                                                     \
      _Pragma("unroll") for (int rt = 0; rt < 4; ++rt) {                       \
        int row = wm * 64 + rt * 16 + col;                                     \
        af[rt] = *(const short8*)&As[row * 64 + (((ks * 4 + quad) ^ (row & 7)) * 8)]; \
      }                                                                        \
      _Pragma("unroll") for (int ct = 0; ct < 4; ++ct) {                       \
        int row = wn * 64 + ct * 16 + col;                                     \
        bf[ct] = *(const short8*)&Bs[row * 64 + (((ks * 4 + quad) ^ (row & 7)) * 8)]; \
      }                                                                        \
      _Pragma("unroll") for (int rt = 0; rt < 4; ++rt)                         \
          _Pragma("unroll") for (int ct = 0; ct < 4; ++ct)                     \
              acc[rt][ct] = MFMA16(af[rt], bf[ct], acc[rt][ct]);               \
    }                                                                          \
  }

__global__ __launch_bounds__(256)
void gemm_qkv(const unsigned short* __restrict__ A, const unsigned short* __restrict__ Bt,
              const float* __restrict__ bq, const float* __restrict__ bk,
              const float* __restrict__ bv,
              unsigned short* __restrict__ Qo, unsigned short* __restrict__ Ko,
              unsigned short* __restrict__ Vo) {
  GEMM_PROLOGUE()
  const int nseg = n0 >> 10;
  const float* bias = (nseg == 0) ? bq : ((nseg == 1) ? bk : bv);
#pragma unroll
  for (int rt = 0; rt < 4; ++rt) {
#pragma unroll
    for (int ct = 0; ct < 4; ++ct) {
      int mg = m0 + wm * 64 + rt * 16 + quad * 4;
      int ng = n0 + wn * 64 + ct * 16 + col;
      int c = ng & 1023;
      int hh = c >> 6, hd = c & 63;
      int b_ = mg >> 11, s = mg & 2047;
      float bb = bias[c];
      if (nseg == 2) {
        ushortx4 pk;
#pragma unroll
        for (int i = 0; i < 4; ++i) pk[i] = f2bf(acc[rt][ct][i] + bb);
        *(ushortx4*)&Vo[(size_t)(b_ * 16 + hh) * 131072 + (size_t)hd * 2048 + s] = pk;
      } else {
        unsigned short* dst =
            ((nseg == 0) ? Qo : Ko) + ((size_t)(b_ * 16 + hh) * 2048 + s) * 64 + hd;
        float scl = (nseg == 0) ? 0.125f : 1.0f;    // fold 1/sqrt(64) into Q
#pragma unroll
        for (int i = 0; i < 4; ++i) dst[(size_t)i * 64] = f2bf((acc[rt][ct][i] + bb) * scl);
      }
    }
  }
}

__global__ __launch_bounds__(256)
void gemm_out(const unsigned short* __restrict__ A, const unsigned short* __restrict__ Bt,
              const float* __restrict__ bo, float* __restrict__ Out) {
  GEMM_PROLOGUE()
#pragma unroll
  for (int rt = 0; rt < 4; ++rt) {
#pragma unroll
    for (int ct = 0; ct < 4; ++ct) {
      int mg = m0 + wm * 64 + rt * 16 + quad * 4;
      int ng = n0 + wn * 64 + ct * 16 + col;
      float bb = bo[ng];
#pragma unroll
      for (int i = 0; i < 4; ++i)
        Out[(size_t)(mg + i) * 1024 + ng] = acc[rt][ct][i] + bb;
    }
  }
}

// ---------------- flash attention v6 (= verified v3 structure, occupancy-fixed) ----
// Q-tile = 64 rows, kv-tile = 128, 4 waves/block, each wave owns 16 q rows.
// Grid 1024 (one tile per block, UNPAIRED): 3 blocks/CU resident (48 KiB LDS,
// launch_bounds(256,3)) -> 12 waves/CU; longest tiles dispatched first so
// backfill balances the 1..17-iteration spread.
__global__ __launch_bounds__(256, 3)
void flash_attn(const unsigned short* __restrict__ Q, const unsigned short* __restrict__ K,
                const unsigned short* __restrict__ Vt, const float* __restrict__ mask,
                unsigned short* __restrict__ O) {
  __shared__ __align__(16) unsigned short Ks[128 * 64];   // [r][c8], chunk^(r&7)
  __shared__ __align__(16) unsigned short Vs[64 * 128];   // [r][c16], chunk^(r&15)
  __shared__ __align__(16) unsigned short Ps[64 * 128];   // P [q][c16] chunk^col; Q stage [64][64]

  const int tid = threadIdx.x;
  const int lane = tid & 63;
  const int wid = tid >> 6;
  const int col = lane & 15;
  const int quad = lane >> 4;
  const int j = 31 - (int)(blockIdx.x >> 5);  // q-tile (64 rows), longest first
  const int bh = blockIdx.x & 31;
  const int b = bh >> 4, h = bh & 15;
  const int q0 = j * 64;
  const int tdiag = j >> 1;                   // diagonal kv-tile (128 wide)

  const unsigned short* Qp = Q + (size_t)bh * 2048 * 64;
  const unsigned short* Kp = K + (size_t)bh * 2048 * 64;
  const unsigned short* Vp = Vt + (size_t)bh * 64 * 2048;
  const float* mp = mask + b * 2048;

  const int lr8 = lane >> 3, lc8 = lane & 7;    // K/Q staging lane coords (8 rows x 8 chunks)
  const int lr16 = lane >> 4, lc16 = lane & 15; // V staging lane coords (4 rows x 16 chunks)
  const floatx4 fzero = (floatx4)(0.f);
  const floatx4 fone = (floatx4)(1.f);

  // stage own Q rows [64][64] into Ps (swizzled): LDS[r][c] = Q[r][c ^ (r&7)]
#pragma unroll
  for (int i = 0; i < 2; ++i) {
    int seg = wid * 2 + i;
    int r = seg * 8 + lr8;
    gload_lds16(Qp + (size_t)(q0 + r) * 64 + ((lc8 ^ (r & 7)) * 8), Ps + seg * 512);
  }
  __syncthreads();  // lgkm+vm drained: staged Q visible
  short8 qf[2];
  {
    int q = wid * 16 + col;
#pragma unroll
    for (int ks = 0; ks < 2; ++ks)
      qf[ks] = *(const short8*)&Ps[q * 64 + (((ks * 4 + quad) ^ (q & 7)) * 8)];
  }
  // First P write is ordered after all waves' qf reads by the t=0 post-staging barrier.

  floatx4 o[4];
#pragma unroll
  for (int dt = 0; dt < 4; ++dt) o[dt] = fzero;
  float mrow = -1e30f;
  float lrow = 0.f;

#pragma unroll 1
  for (int t = 0; t <= tdiag; ++t) {
    if (t > 0) __syncthreads();  // prior iter's Ks/Vs frag reads done
#pragma unroll
    for (int i = 0; i < 4; ++i) {  // K tile [128][64]
      int seg = wid * 4 + i;
      int r = seg * 8 + lr8;
      gload_lds16(Kp + (size_t)(t * 128 + r) * 64 + ((lc8 ^ (r & 7)) * 8), Ks + seg * 512);
    }
#pragma unroll
    for (int i = 0; i < 4; ++i) {  // V^T tile [64][128]
      int seg = wid * 4 + i;
      int r = seg * 4 + lr16;
      gload_lds16(Vp + (size_t)r * 2048 + t * 128 + ((lc16 ^ (r & 15)) * 8), Vs + seg * 512);
    }
    __syncthreads();  // staging visible (vmcnt drained by barrier semantics)

    // padding-mask additive bias (kv = rt*16 + quad*4 + i), L1-resident
    floatx4 mbias[8];
#pragma unroll
    for (int rt = 0; rt < 8; ++rt) {
      floatx4 mm = *(const floatx4*)&mp[t * 128 + rt * 16 + quad * 4];
      mbias[rt] = (fone - mm) * -1.0e9f;
    }

    // S^T: [kv=128][q=16 per wave]
    floatx4 sc[8];
#pragma unroll
    for (int rt = 0; rt < 8; ++rt) {
      int kr = rt * 16 + col;
      short8 kf0 = *(const short8*)&Ks[kr * 64 + ((quad ^ (col & 7)) * 8)];
      short8 kf1 = *(const short8*)&Ks[kr * 64 + (((4 + quad) ^ (col & 7)) * 8)];
      floatx4 s0 = MFMA16(kf0, qf[0], fzero);
      s0 = MFMA16(kf1, qf[1], s0);
      sc[rt] = s0 + mbias[rt];
    }
    if (t == tdiag) {  // diagonal tile: causal mask, exactly -1e9 like the reference
      int qg = q0 + wid * 16 + col;
#pragma unroll
      for (int rt = 0; rt < 8; ++rt)
#pragma unroll
        for (int i = 0; i < 4; ++i)
          if (t * 128 + rt * 16 + quad * 4 + i > qg) sc[rt][i] = -1.0e9f;
    }

    // online softmax (per-lane q row stats; reduce over quad via 2 shuffles)
    float mt = -1e30f;
#pragma unroll
    for (int rt = 0; rt < 8; ++rt)
      mt = fmaxf(mt, fmaxf(fmaxf(sc[rt][0], sc[rt][1]), fmaxf(sc[rt][2], sc[rt][3])));
    mt = fmaxf(mt, __shfl_xor(mt, 16));
    mt = fmaxf(mt, __shfl_xor(mt, 32));
    float mn = fmaxf(mrow, mt);
    float alpha = __expf(mrow - mn);
    mrow = mn;
    float sum = 0.f;
#pragma unroll
    for (int rt = 0; rt < 8; ++rt)
#pragma unroll
      for (int i = 0; i < 4; ++i) {
        float p = __expf(sc[rt][i] - mn);
        sc[rt][i] = p;
        sum += p;
      }
    sum += __shfl_xor(sum, 16);
    sum += __shfl_xor(sum, 32);
    lrow = lrow * alpha + sum;
#pragma unroll
    for (int dt = 0; dt < 4; ++dt) o[dt] *= alpha;
    // write P rows (own wave) swizzled: 8B at chunk (rt*2 + quad>>1) ^ col, half quad&1
    {
      int qloc = wid * 16 + col;
#pragma unroll
      for (int rt = 0; rt < 8; ++rt) {
        ushortx4 pk;
#pragma unroll
        for (int i = 0; i < 4; ++i) pk[i] = f2bf(sc[rt][i]);
        int chunk = (rt * 2 + (quad >> 1)) ^ col;
        *(ushortx4*)&Ps[qloc * 128 + chunk * 8 + (quad & 1) * 4] = pk;
      }
    }
    // PV: O^T[d][q] += V^T * P^T (own-wave P rows; DS in-order per wave, no barrier)
#pragma unroll
    for (int ks = 0; ks < 4; ++ks) {
      int ch = ks * 4 + quad;
      short8 pf = *(const short8*)&Ps[(wid * 16 + col) * 128 + ((ch ^ col) * 8)];
#pragma unroll
      for (int dt = 0; dt < 4; ++dt) {
        short8 vf = *(const short8*)&Vs[(dt * 16 + col) * 128 + ((ch ^ col) * 8)];
        o[dt] = MFMA16(vf, pf, o[dt]);
      }
    }
  }

  // epilogue: O^T regs: d = dt*16 + quad*4 + i, q = wid*16 + col
  {
    float inv = 1.0f / lrow;
    int qg = q0 + wid * 16 + col;
    unsigned short* dst = O + ((size_t)(b * 2048 + qg)) * 1024 + h * 64;
#pragma unroll
    for (int dt = 0; dt < 4; ++dt) {
      ushortx4 pk;
#pragma unroll
      for (int i = 0; i < 4; ++i) pk[i] = f2bf(o[dt][i] * inv);
      *(ushortx4*)&dst[dt * 16 + quad * 4] = pk;
    }
  }
}

// ---------------- launch ----------------
extern "C" void kernel_launch(void* const* d_in, const int* in_sizes, int n_in,
                              void* d_out, int out_size, void* d_ws, size_t ws_size,
                              hipStream_t stream) {
  (void)in_sizes; (void)n_in; (void)out_size; (void)ws_size;
  const float* x  = (const float*)d_in[0];
  const float* mask = (const float*)d_in[1];
  const float* Wq = (const float*)d_in[2];
  const float* bq = (const float*)d_in[3];
  const float* Wk = (const float*)d_in[4];
  const float* bk = (const float*)d_in[5];
  const float* Wv = (const float*)d_in[6];
  const float* bv = (const float*)d_in[7];
  const float* Wo = (const float*)d_in[8];
  const float* bo = (const float*)d_in[9];
  float* out = (float*)d_out;

  char* ws = (char*)d_ws;
  unsigned short* xb    = (unsigned short*)(ws);                    // 8 MB
  unsigned short* Wqkvt = (unsigned short*)(ws + (8u << 20));       // 6 MB
  unsigned short* Wot   = (unsigned short*)(ws + (14u << 20));      // 2 MB
  unsigned short* Qb    = (unsigned short*)(ws + (16u << 20));      // 8 MB
  unsigned short* Kb    = (unsigned short*)(ws + (24u << 20));      // 8 MB
  unsigned short* Vtb   = (unsigned short*)(ws + (32u << 20));      // 8 MB
  unsigned short* Ao    = (unsigned short*)(ws + (40u << 20));      // 8 MB (48 MB total)

  convert_x<<<4096, 256, 0, stream>>>(x, xb);
  transpose_w<<<dim3(32, 32, 4), dim3(32, 8), 0, stream>>>(Wq, Wk, Wv, Wo, Wqkvt, Wot);
  gemm_qkv<<<dim3(32, 24), 256, 0, stream>>>(xb, Wqkvt, bq, bk, bv, Qb, Kb, Vtb);
  flash_attn<<<dim3(1024), 256, 0, stream>>>(Qb, Kb, Vtb, mask, Ao);
  gemm_out<<<dim3(32, 8), 256, 0, stream>>>(Ao, Wot, bo, out);
}